// Round 7
// baseline (327.168 us; speedup 1.0000x reference)
//
#include <hip/hip_runtime.h>
#include <hip/hip_bf16.h>
#include <math.h>

using bf16 = __hip_bfloat16;
typedef __attribute__((ext_vector_type(8))) short short8;
typedef __attribute__((ext_vector_type(4))) float f32x4;
typedef __attribute__((ext_vector_type(4))) unsigned int u32x4;

#define BATCH 8192
#define SDIM  70
#define NS    64
#define HID   1024
#define NA    4096
#define KPAD  128   // states K padded 70 -> 128 (multiple of 64 for BK=64)

// async global->LDS, 16 B per lane. LDS dest is wave-uniform base + lane*16.
__device__ __forceinline__ void gld_lds16(const bf16* g, bf16* l) {
    __builtin_amdgcn_global_load_lds(
        (const __attribute__((address_space(1))) void*)g,
        (__attribute__((address_space(3))) void*)l, 16, 0, 0);
}

__device__ __forceinline__ short f2bf(float v) {
    union { bf16 b; short s; } u; u.b = __float2bfloat16(v); return u.s;
}

// ---------------- fused prep kernel ----------------
// block ranges:
//   [0,512)       : states fp32[8192][70] -> bf16[8192][128] zero-padded (8 cols/thread)
//   [512,640)     : W1 [70][1024]   -> w1bt [1024][128]
//   [640,1664)    : W2 [1024][1024] -> w2bt [1024][1024]
//   [1664,5760)   : Wh [1024][4096] -> whbt [4096][1024]
//   [5760,5776)   : pact (5-bit x6 SWAR pack of action_space)
//   [5776,5808)   : trow (5-bit x6 SWAR pack of floor(waitlist) per batch row)
//   [5808,5840)   : zero rowsum[8192] (accumulated by G3's epilogue via atomics)
__device__ __forceinline__ void tr32(const float* __restrict__ in, bf16* __restrict__ out,
                                     int K, int N, int Kpad, int bx, int by, int t,
                                     float (*tile)[33]) {
    int kb = by * 32, nb = bx * 32;
    int tx = t & 31, ty = t >> 5;
    #pragma unroll
    for (int i = 0; i < 32; i += 8) {
        int k = kb + ty + i, n = nb + tx;
        tile[ty + i][tx] = (k < K) ? in[(size_t)k * N + n] : 0.0f;
    }
    __syncthreads();
    #pragma unroll
    for (int i = 0; i < 32; i += 8) {
        int n = nb + ty + i, k = kb + tx;
        if (k < Kpad) out[(size_t)n * Kpad + k] = __float2bfloat16(tile[tx][ty + i]);
    }
}

__global__ __launch_bounds__(256)
void prep_k(const float* __restrict__ states, const float* __restrict__ W1,
            const float* __restrict__ W2, const float* __restrict__ Wh,
            const int* __restrict__ act,
            bf16* __restrict__ statesb, bf16* __restrict__ w1bt,
            bf16* __restrict__ w2bt, bf16* __restrict__ whbt,
            unsigned* __restrict__ pact, unsigned* __restrict__ trow,
            float* __restrict__ rowsum) {
    __shared__ float tile[32][33];
    const int b = blockIdx.x, t = threadIdx.x;
    if (b < 512) {
        int idx = b * 256 + t;                 // 131072 threads, 8 cols each
        int row = idx >> 4;                    // 16 threads per row
        int c0  = (idx & 15) * 8;
        const float* src = states + (size_t)row * SDIM;
        short8 o;
        #pragma unroll
        for (int i = 0; i < 8; i++) {
            int c = c0 + i;
            o[i] = f2bf((c < SDIM) ? src[c] : 0.0f);
        }
        *(short8*)&statesb[(size_t)row * KPAD + c0] = o;
    } else if (b < 640) {
        int r = b - 512;                       // 32 nb x 4 kb
        tr32(W1, w1bt, SDIM, HID, KPAD, r & 31, r >> 5, t, tile);
    } else if (b < 1664) {
        int r = b - 640;                       // 32 x 32
        tr32(W2, w2bt, HID, HID, HID, r & 31, r >> 5, t, tile);
    } else if (b < 5760) {
        int r = b - 1664;                      // 128 nb x 32 kb
        tr32(Wh, whbt, HID, NA, HID, r & 127, r >> 7, t, tile);
    } else if (b < 5776) {
        int c = (b - 5760) * 256 + t;
        if (c < NA) {
            const int* a = act + c * 6;
            unsigned p = 0;
            #pragma unroll
            for (int i = 0; i < 6; i++) p |= ((unsigned)a[i]) << (5 * i);
            pact[c] = p;
        }
    } else if (b < 5808) {
        int row = (b - 5776) * 256 + t;        // 32*256 = 8192 rows exactly
        const float* wl = states + (size_t)row * SDIM + NS;
        unsigned T = 0;
        #pragma unroll
        for (int i = 0; i < 6; i++) T |= ((unsigned)(int)wl[i]) << (5 * i);
        trow[row] = T;
    } else {
        int idx = (b - 5808) * 256 + t;        // zero rowsum[8192]
        rowsum[idx] = 0.0f;
    }
}

// ---------------- bf16 MFMA GEMM: 128xBN tile, BK=64, swizzled LDS ----------------
// C[M][N] = epilogue(A[M][K] @ BT[N][K]^T + bias)
// MODE 0: tanh -> bf16; MODE 1: raw -> fp32; MODE 2: raw -> bf16;
// MODE 3: exp(raw + log-mask) -> bf16 (UNNORMALIZED probs) + per-row sum
//         accumulated into rowsum[] via fp32 atomics (64 atomics/row total).
//         exp taken on the fp32 accumulator (pre-bf16) -- more accurate than
//         the old store-bf16-logit-then-exp path.
// BN = 128: 4 waves, wave tile 64x64, acc[4][4]  (grid-rich dispatches)
// BN = 64 : 4 waves, wave tile 64x32, acc[4][2]  (2x blocks for occupancy-starved
//           N=1024 dispatches: 512 -> 1024 blocks, LDS 32 -> 24 KB)
// Block mapping: plain 2-D, blockIdx.x = n-block (fast) -> consecutive blocks share
// the same A-panel (256 KB, L2-resident). Measured FETCH 82 MB; both XCD remaps
// regressed (r1: +0, r5: 3.3x FETCH) -- do not touch.
// LDS layout: row r (128 B = 8 chunks of 16 B); slot c holds global k-chunk c^(r&7).
// K must be a multiple of 64.
template<int MODE, int BN>
__global__ __launch_bounds__(256)
void gemm128(const bf16* __restrict__ A, const bf16* __restrict__ BT,
             const float* __restrict__ bias, void* __restrict__ Cout,
             int M, int N, int K,
             const unsigned* __restrict__ trow, const unsigned* __restrict__ pact,
             float* __restrict__ rowsum) {
    const int n0 = blockIdx.x * BN;
    const int m0 = blockIdx.y * 128;
    const int tid  = threadIdx.x;
    const int wave = tid >> 6;
    const int lane = tid & 63;

    constexpr int NJ = BN / 32;        // acc cols per wave
    constexpr int BCH = BN / 8;        // 8-row staging chunks in B

    __shared__ __align__(16) bf16 As[128 * 64];   // 16 KB
    __shared__ __align__(16) bf16 Bs[BN * 64];    // 16 KB (BN=128) / 8 KB (BN=64)

    // staging: round q, wave w -> 8-row chunk (q*4+w); lane l -> row +(l>>3),
    // LDS slot (l&7); global k-chunk (l&7)^(l>>3)  [XOR swizzle]
    const int lr = lane >> 3;                     // 0..7
    const int gk = ((lane & 7) ^ lr) * 8;         // swizzled global k offset
    const bf16* ag = A  + (size_t)(m0 + lr) * K + gk;
    const bf16* bg = BT + (size_t)(n0 + lr) * K + gk;

    f32x4 acc[4][NJ];
    #pragma unroll
    for (int i = 0; i < 4; i++)
        #pragma unroll
        for (int j = 0; j < NJ; j++) acc[i][j] = (f32x4){0.f, 0.f, 0.f, 0.f};

    const int rb = (wave >> 1) * 64;        // wave's m block within tile
    const int cb = (wave & 1) * (BN / 2);   // wave's n block within tile
    const int fr = lane & 15;
    const int kq = lane >> 4;               // 0..3: which 8-elem chunk of the 32-k step

    // K-invariant LDS fragment byte offsets (r&7 == fr&7 since rb,i*16 are mult of 8)
    int aoff[2][4], boff[2][NJ];
    #pragma unroll
    for (int kk = 0; kk < 2; kk++) {
        const int cbase = kk * 4 + kq;
        #pragma unroll
        for (int i = 0; i < 4; i++) {
            const int ra = rb + i * 16 + fr;
            aoff[kk][i] = (ra * 64 + ((cbase ^ (fr & 7)) * 8)) * 2;
        }
        #pragma unroll
        for (int j = 0; j < NJ; j++) {
            const int rn = cb + j * 16 + fr;
            boff[kk][j] = (rn * 64 + ((cbase ^ (fr & 7)) * 8)) * 2;
        }
    }
    const char* Asb = (const char*)As;
    const char* Bsb = (const char*)Bs;

    for (int k0 = 0; k0 < K; k0 += 64) {
        #pragma unroll
        for (int q = 0; q < 4; q++) {
            const int ch = q * 4 + wave;          // 8-row chunk id (wave-uniform)
            gld_lds16(ag + (size_t)(ch * 8) * K + k0, &As[ch * 512]);
            if (ch < BCH)
                gld_lds16(bg + (size_t)(ch * 8) * K + k0, &Bs[ch * 512]);
        }
        __syncthreads();

        #pragma unroll
        for (int kk = 0; kk < 2; kk++) {          // two 32-k MFMA steps
            short8 af[4], bfr[NJ];
            #pragma unroll
            for (int i = 0; i < 4; i++)  af[i]  = *(const short8*)(Asb + aoff[kk][i]);
            #pragma unroll
            for (int j = 0; j < NJ; j++) bfr[j] = *(const short8*)(Bsb + boff[kk][j]);
            #pragma unroll
            for (int i = 0; i < 4; i++)
                #pragma unroll
                for (int j = 0; j < NJ; j++)
                    acc[i][j] = __builtin_amdgcn_mfma_f32_16x16x32_bf16(af[i], bfr[j], acc[i][j], 0, 0, 0);
        }
        __syncthreads();
    }

    // C/D layout: col = lane&15, row = (lane>>4)*4 + r
    const int orow = m0 + rb + (lane >> 4) * 4;
    const int ocol = n0 + cb + fr;
    float bv[NJ];
    #pragma unroll
    for (int j = 0; j < NJ; j++) bv[j] = bias[ocol + j * 16];
    unsigned pv[NJ];
    if (MODE == 3) {
        #pragma unroll
        for (int j = 0; j < NJ; j++) pv[j] = pact[ocol + j * 16];
    }
    const unsigned H = 0x21084210u;   // guard bit (bit4) of each 5-bit field
    #pragma unroll
    for (int i = 0; i < 4; i++) {
        #pragma unroll
        for (int r = 0; r < 4; r++) {
            const int row = orow + i * 16 + r;
            unsigned TH = 0;
            if (MODE == 3) TH = trow[row] | H;
            float rs = 0.f;
            #pragma unroll
            for (int j = 0; j < NJ; j++) {
                float val = acc[i][j][r] + bv[j];
                const size_t off = (size_t)row * N + ocol + j * 16;
                if (MODE == 0) {
                    ((bf16*)Cout)[off] = __float2bfloat16(tanhf(val));
                } else if (MODE == 1) {
                    ((float*)Cout)[off] = val;
                } else if (MODE == 3) {
                    // infeasible <=> some 5-bit field of pact exceeds trow field
                    if (((TH - pv[j]) & H) != H) val -= 20.7232658f;   // + log(1e-9)
                    float e = __expf(val);                              // fp32-accurate
                    ((bf16*)Cout)[off] = __float2bfloat16(e);           // unnormalized
                    rs += e;
                } else {
                    ((bf16*)Cout)[off] = __float2bfloat16(val);
                }
            }
            if (MODE == 3) {
                // reduce this row's 4-col partial across the 16-lane fr group
                rs += __shfl_xor(rs, 1, 64);
                rs += __shfl_xor(rs, 2, 64);
                rs += __shfl_xor(rs, 4, 64);
                rs += __shfl_xor(rs, 8, 64);
                if (fr == 0) atomicAdd(&rowsum[row], rs);
            }
        }
    }
}

// ---------------- normalize: bf16 unnormalized exps -> fp32 probs ----------------
// one block per row (256 threads x 16 cols). Pure streaming: no LDS, no barriers,
// no exp -- G3's epilogue already produced exp values and the row sums.
__global__ __launch_bounds__(256)
void normalize_k(const bf16* __restrict__ expb, const float* __restrict__ rowsum,
                 float* __restrict__ out) {
    const int row = blockIdx.x;
    const int t   = threadIdx.x;

    const float inv = 1.0f / rowsum[row];   // same address across block -> cache broadcast

    const unsigned* lrow = (const unsigned*)(expb + (size_t)row * NA) + t * 8;
    u32x4 raw0 = *(const u32x4*)lrow;
    u32x4 raw1 = *(const u32x4*)(lrow + 4);
    unsigned rw[8];
    #pragma unroll
    for (int i = 0; i < 4; i++) { rw[i] = raw0[i]; rw[4 + i] = raw1[i]; }

    float* orow = out + (size_t)row * NA + t * 16;
    #pragma unroll
    for (int q = 0; q < 2; q++) {
        f32x4 o0, o1;
        #pragma unroll
        for (int e = 0; e < 4; e++) {
            unsigned w = rw[q * 4 + e];
            float lo = __uint_as_float(w << 16);
            float hi = __uint_as_float(w & 0xffff0000u);
            if (e < 2) { o0[2 * e] = lo * inv; o0[2 * e + 1] = hi * inv; }
            else       { o1[2 * (e - 2)] = lo * inv; o1[2 * (e - 2) + 1] = hi * inv; }
        }
        *(f32x4*)(orow + q * 8)     = o0;
        *(f32x4*)(orow + q * 8 + 4) = o1;
    }
}

// ---------------- launch ----------------
extern "C" void kernel_launch(void* const* d_in, const int* in_sizes, int n_in,
                              void* d_out, int out_size, void* d_ws, size_t ws_size,
                              hipStream_t stream) {
    const float* states = (const float*)d_in[0];
    const float* W1 = (const float*)d_in[1];
    const float* b1 = (const float*)d_in[2];
    const float* W2 = (const float*)d_in[3];
    const float* b2 = (const float*)d_in[4];
    const float* Wh = (const float*)d_in[5];
    const float* bh = (const float*)d_in[6];
    const int*   act = (const int*)d_in[7];
    float* out = (float*)d_out;

    char* ws = (char*)d_ws;
    bf16* statesb = (bf16*)ws; ws += (size_t)BATCH * KPAD * 2;
    bf16* w1bt    = (bf16*)ws; ws += (size_t)HID * KPAD * 2;
    bf16* w2bt    = (bf16*)ws; ws += (size_t)HID * HID * 2;
    bf16* whbt    = (bf16*)ws; ws += (size_t)NA * HID * 2;
    bf16* h1      = (bf16*)ws; ws += (size_t)BATCH * HID * 2;
    bf16* h2      = (bf16*)ws; ws += (size_t)BATCH * HID * 2;
    bf16* expb    = (bf16*)ws; ws += (size_t)BATCH * NA * 2;
    unsigned* pact = (unsigned*)ws; ws += (size_t)NA * 4;
    unsigned* trow = (unsigned*)ws; ws += (size_t)BATCH * 4;
    float* rowsum  = (float*)ws;   ws += (size_t)BATCH * 4;

    prep_k<<<5840, 256, 0, stream>>>(states, W1, W2, Wh, act,
                                     statesb, w1bt, w2bt, whbt, pact, trow, rowsum);

    // G1/G2: N=1024 -> BN=64 tiles (1024 blocks; occupancy fix, round 6: -24 us)
    gemm128<0, 64><<<dim3(HID / 64, BATCH / 128), 256, 0, stream>>>(
        statesb, w1bt, b1, h1, BATCH, HID, KPAD, nullptr, nullptr, nullptr);
    gemm128<0, 64><<<dim3(HID / 64, BATCH / 128), 256, 0, stream>>>(
        h1, w2bt, b2, h2, BATCH, HID, HID, nullptr, nullptr, nullptr);
    // logits GEMM: fused mask + exp + per-row sum (splits softmax across the epilogue)
    gemm128<3, 128><<<dim3(NA / 128, BATCH / 128), 256, 0, stream>>>(
        h2, whbt, bh, expb, BATCH, NA, HID, trow, pact, rowsum);

    normalize_k<<<BATCH, 256, 0, stream>>>(expb, rowsum, out);
}

// Round 8
// 294.555 us; speedup vs baseline: 1.1107x; 1.1107x over previous
//
#include <hip/hip_runtime.h>
#include <hip/hip_bf16.h>
#include <math.h>

using bf16 = __hip_bfloat16;
typedef __attribute__((ext_vector_type(8))) short short8;
typedef __attribute__((ext_vector_type(4))) float f32x4;
typedef __attribute__((ext_vector_type(4))) unsigned int u32x4;

#define BATCH 8192
#define SDIM  70
#define NS    64
#define HID   1024
#define NA    4096
#define KPAD  128   // states K padded 70 -> 128 (multiple of 64 for BK=64)

// async global->LDS, 16 B per lane. LDS dest is wave-uniform base + lane*16.
__device__ __forceinline__ void gld_lds16(const bf16* g, bf16* l) {
    __builtin_amdgcn_global_load_lds(
        (const __attribute__((address_space(1))) void*)g,
        (__attribute__((address_space(3))) void*)l, 16, 0, 0);
}

__device__ __forceinline__ short f2bf(float v) {
    union { bf16 b; short s; } u; u.b = __float2bfloat16(v); return u.s;
}

// ---------------- fused prep kernel ----------------
// block ranges:
//   [0,512)       : states fp32[8192][70] -> bf16[8192][128] zero-padded (8 cols/thread)
//   [512,640)     : W1 [70][1024]   -> w1bt [1024][128]
//   [640,1664)    : W2 [1024][1024] -> w2bt [1024][1024]
//   [1664,5760)   : Wh [1024][4096] -> whbt [4096][1024]
//   [5760,5776)   : pact (5-bit x6 SWAR pack of action_space)
//   [5776,5808)   : trow (5-bit x6 SWAR pack of floor(waitlist) per batch row)
__device__ __forceinline__ void tr32(const float* __restrict__ in, bf16* __restrict__ out,
                                     int K, int N, int Kpad, int bx, int by, int t,
                                     float (*tile)[33]) {
    int kb = by * 32, nb = bx * 32;
    int tx = t & 31, ty = t >> 5;
    #pragma unroll
    for (int i = 0; i < 32; i += 8) {
        int k = kb + ty + i, n = nb + tx;
        tile[ty + i][tx] = (k < K) ? in[(size_t)k * N + n] : 0.0f;
    }
    __syncthreads();
    #pragma unroll
    for (int i = 0; i < 32; i += 8) {
        int n = nb + ty + i, k = kb + tx;
        if (k < Kpad) out[(size_t)n * Kpad + k] = __float2bfloat16(tile[tx][ty + i]);
    }
}

__global__ __launch_bounds__(256)
void prep_k(const float* __restrict__ states, const float* __restrict__ W1,
            const float* __restrict__ W2, const float* __restrict__ Wh,
            const int* __restrict__ act,
            bf16* __restrict__ statesb, bf16* __restrict__ w1bt,
            bf16* __restrict__ w2bt, bf16* __restrict__ whbt,
            unsigned* __restrict__ pact, unsigned* __restrict__ trow) {
    __shared__ float tile[32][33];
    const int b = blockIdx.x, t = threadIdx.x;
    if (b < 512) {
        int idx = b * 256 + t;                 // 131072 threads, 8 cols each
        int row = idx >> 4;                    // 16 threads per row
        int c0  = (idx & 15) * 8;
        const float* src = states + (size_t)row * SDIM;
        short8 o;
        #pragma unroll
        for (int i = 0; i < 8; i++) {
            int c = c0 + i;
            o[i] = f2bf((c < SDIM) ? src[c] : 0.0f);
        }
        *(short8*)&statesb[(size_t)row * KPAD + c0] = o;
    } else if (b < 640) {
        int r = b - 512;                       // 32 nb x 4 kb
        tr32(W1, w1bt, SDIM, HID, KPAD, r & 31, r >> 5, t, tile);
    } else if (b < 1664) {
        int r = b - 640;                       // 32 x 32
        tr32(W2, w2bt, HID, HID, HID, r & 31, r >> 5, t, tile);
    } else if (b < 5760) {
        int r = b - 1664;                      // 128 nb x 32 kb
        tr32(Wh, whbt, HID, NA, HID, r & 127, r >> 7, t, tile);
    } else if (b < 5776) {
        int c = (b - 5760) * 256 + t;
        if (c < NA) {
            const int* a = act + c * 6;
            unsigned p = 0;
            #pragma unroll
            for (int i = 0; i < 6; i++) p |= ((unsigned)a[i]) << (5 * i);
            pact[c] = p;
        }
    } else {
        int row = (b - 5776) * 256 + t;        // 32*256 = 8192 rows exactly
        const float* wl = states + (size_t)row * SDIM + NS;
        unsigned T = 0;
        #pragma unroll
        for (int i = 0; i < 6; i++) T |= ((unsigned)(int)wl[i]) << (5 * i);
        trow[row] = T;
    }
}

// ---------------- bf16 MFMA GEMM: 128xBN tile, BK=64, swizzled LDS ----------------
// C[M][N] = epilogue(A[M][K] @ BT[N][K]^T + bias)
// MODE 0: tanh -> bf16; MODE 1: raw -> fp32; MODE 2: raw -> bf16;
// MODE 3: raw + log-mask (SWAR feasibility vs trow/pact) -> bf16
// BN = 128: 4 waves, wave tile 64x64, acc[4][4]  (grid-rich dispatches)
// BN = 64 : 4 waves, wave tile 64x32, acc[4][2]  (2x blocks for occupancy-starved
//           N=1024 dispatches: 512 -> 1024 blocks, LDS 32 -> 24 KB)
// Block mapping: plain 2-D, blockIdx.x = n-block (fast) -> consecutive blocks share
// the same A-panel (256 KB, L2-resident). Measured FETCH 82 MB; both XCD remaps
// regressed (r1: +0, r5: 3.3x FETCH) -- do not touch.
// Round-7 lesson: fusing exp+rowsum into the MODE-3 epilogue regressed (+12 us
// total, atomics +8 MB writes, no G3 gain) -- reverted; keep the split softmax.
// LDS layout: row r (128 B = 8 chunks of 16 B); slot c holds global k-chunk c^(r&7).
// K must be a multiple of 64.
template<int MODE, int BN>
__global__ __launch_bounds__(256)
void gemm128(const bf16* __restrict__ A, const bf16* __restrict__ BT,
             const float* __restrict__ bias, void* __restrict__ Cout,
             int M, int N, int K,
             const unsigned* __restrict__ trow, const unsigned* __restrict__ pact) {
    const int n0 = blockIdx.x * BN;
    const int m0 = blockIdx.y * 128;
    const int tid  = threadIdx.x;
    const int wave = tid >> 6;
    const int lane = tid & 63;

    constexpr int NJ = BN / 32;        // acc cols per wave
    constexpr int BCH = BN / 8;        // 8-row staging chunks in B

    __shared__ __align__(16) bf16 As[128 * 64];   // 16 KB
    __shared__ __align__(16) bf16 Bs[BN * 64];    // 16 KB (BN=128) / 8 KB (BN=64)

    // staging: round q, wave w -> 8-row chunk (q*4+w); lane l -> row +(l>>3),
    // LDS slot (l&7); global k-chunk (l&7)^(l>>3)  [XOR swizzle]
    const int lr = lane >> 3;                     // 0..7
    const int gk = ((lane & 7) ^ lr) * 8;         // swizzled global k offset
    const bf16* ag = A  + (size_t)(m0 + lr) * K + gk;
    const bf16* bg = BT + (size_t)(n0 + lr) * K + gk;

    f32x4 acc[4][NJ];
    #pragma unroll
    for (int i = 0; i < 4; i++)
        #pragma unroll
        for (int j = 0; j < NJ; j++) acc[i][j] = (f32x4){0.f, 0.f, 0.f, 0.f};

    const int rb = (wave >> 1) * 64;        // wave's m block within tile
    const int cb = (wave & 1) * (BN / 2);   // wave's n block within tile
    const int fr = lane & 15;
    const int kq = lane >> 4;               // 0..3: which 8-elem chunk of the 32-k step

    // K-invariant LDS fragment byte offsets (r&7 == fr&7 since rb,i*16 are mult of 8)
    int aoff[2][4], boff[2][NJ];
    #pragma unroll
    for (int kk = 0; kk < 2; kk++) {
        const int cbase = kk * 4 + kq;
        #pragma unroll
        for (int i = 0; i < 4; i++) {
            const int ra = rb + i * 16 + fr;
            aoff[kk][i] = (ra * 64 + ((cbase ^ (fr & 7)) * 8)) * 2;
        }
        #pragma unroll
        for (int j = 0; j < NJ; j++) {
            const int rn = cb + j * 16 + fr;
            boff[kk][j] = (rn * 64 + ((cbase ^ (fr & 7)) * 8)) * 2;
        }
    }
    const char* Asb = (const char*)As;
    const char* Bsb = (const char*)Bs;

    for (int k0 = 0; k0 < K; k0 += 64) {
        #pragma unroll
        for (int q = 0; q < 4; q++) {
            const int ch = q * 4 + wave;          // 8-row chunk id (wave-uniform)
            gld_lds16(ag + (size_t)(ch * 8) * K + k0, &As[ch * 512]);
            if (ch < BCH)
                gld_lds16(bg + (size_t)(ch * 8) * K + k0, &Bs[ch * 512]);
        }
        __syncthreads();

        #pragma unroll
        for (int kk = 0; kk < 2; kk++) {          // two 32-k MFMA steps
            short8 af[4], bfr[NJ];
            #pragma unroll
            for (int i = 0; i < 4; i++)  af[i]  = *(const short8*)(Asb + aoff[kk][i]);
            #pragma unroll
            for (int j = 0; j < NJ; j++) bfr[j] = *(const short8*)(Bsb + boff[kk][j]);
            #pragma unroll
            for (int i = 0; i < 4; i++)
                #pragma unroll
                for (int j = 0; j < NJ; j++)
                    acc[i][j] = __builtin_amdgcn_mfma_f32_16x16x32_bf16(af[i], bfr[j], acc[i][j], 0, 0, 0);
        }
        __syncthreads();
    }

    // C/D layout: col = lane&15, row = (lane>>4)*4 + r
    const int orow = m0 + rb + (lane >> 4) * 4;
    const int ocol = n0 + cb + fr;
    float bv[NJ];
    #pragma unroll
    for (int j = 0; j < NJ; j++) bv[j] = bias[ocol + j * 16];
    unsigned pv[NJ];
    if (MODE == 3) {
        #pragma unroll
        for (int j = 0; j < NJ; j++) pv[j] = pact[ocol + j * 16];
    }
    const unsigned H = 0x21084210u;   // guard bit (bit4) of each 5-bit field
    #pragma unroll
    for (int i = 0; i < 4; i++) {
        #pragma unroll
        for (int r = 0; r < 4; r++) {
            const int row = orow + i * 16 + r;
            unsigned TH = 0;
            if (MODE == 3) TH = trow[row] | H;
            #pragma unroll
            for (int j = 0; j < NJ; j++) {
                float val = acc[i][j][r] + bv[j];
                const size_t off = (size_t)row * N + ocol + j * 16;
                if (MODE == 0) {
                    ((bf16*)Cout)[off] = __float2bfloat16(tanhf(val));
                } else if (MODE == 1) {
                    ((float*)Cout)[off] = val;
                } else if (MODE == 3) {
                    // infeasible <=> some 5-bit field of pact exceeds trow field
                    if (((TH - pv[j]) & H) != H) val -= 20.7232658f;   // + log(1e-9)
                    ((bf16*)Cout)[off] = __float2bfloat16(val);
                } else {
                    ((bf16*)Cout)[off] = __float2bfloat16(val);
                }
            }
        }
    }
}

// ---------------- softmax: bf16 (pre-masked) logits -> fp32 probs ----------------
// ONE WAVE PER ROW (4 rows per 256-thread block): zero barriers, zero LDS.
// Lane l handles 8 strided 16B chunks (coalesced 1KB per wave instruction);
// per-row sum is a 6-step __shfl_xor butterfly.
// No max-subtraction: logits are bounded (|logit| <~ 30), exp fits fp32;
// mathematically identical to softmax (established round 3+, refchecked).
__global__ __launch_bounds__(256)
void softmax_k(const bf16* __restrict__ logitsb, float* __restrict__ out) {
    const int row  = (blockIdx.x << 2) | (threadIdx.x >> 6);   // wave id = row
    const int lane = threadIdx.x & 63;

    const unsigned* lrow = (const unsigned*)(logitsb + (size_t)row * NA);

    float v[64];
    float s = 0.f;
    #pragma unroll
    for (int c = 0; c < 8; c++) {
        // chunk index ch = c*64 + lane -> dword offset ch*4
        u32x4 raw = *(const u32x4*)(lrow + c * 256 + lane * 4);
        #pragma unroll
        for (int e = 0; e < 4; e++) {
            float lo = __expf(__uint_as_float(raw[e] << 16));
            float hi = __expf(__uint_as_float(raw[e] & 0xffff0000u));
            v[c * 8 + 2 * e]     = lo;
            v[c * 8 + 2 * e + 1] = hi;
            s += lo + hi;
        }
    }
    #pragma unroll
    for (int o = 32; o > 0; o >>= 1) s += __shfl_xor(s, o, 64);
    const float inv = 1.0f / s;

    float* orow = out + (size_t)row * NA;
    #pragma unroll
    for (int c = 0; c < 8; c++) {
        const int fbase = c * 512 + lane * 8;   // float offset of this lane's 8 cols
        #pragma unroll
        for (int q = 0; q < 2; q++) {
            f32x4 o4 = { v[c * 8 + q * 4] * inv,     v[c * 8 + q * 4 + 1] * inv,
                         v[c * 8 + q * 4 + 2] * inv, v[c * 8 + q * 4 + 3] * inv };
            *(f32x4*)(orow + fbase + q * 4) = o4;
        }
    }
}

// ---------------- launch ----------------
extern "C" void kernel_launch(void* const* d_in, const int* in_sizes, int n_in,
                              void* d_out, int out_size, void* d_ws, size_t ws_size,
                              hipStream_t stream) {
    const float* states = (const float*)d_in[0];
    const float* W1 = (const float*)d_in[1];
    const float* b1 = (const float*)d_in[2];
    const float* W2 = (const float*)d_in[3];
    const float* b2 = (const float*)d_in[4];
    const float* Wh = (const float*)d_in[5];
    const float* bh = (const float*)d_in[6];
    const int*   act = (const int*)d_in[7];
    float* out = (float*)d_out;

    char* ws = (char*)d_ws;
    bf16* statesb = (bf16*)ws; ws += (size_t)BATCH * KPAD * 2;
    bf16* w1bt    = (bf16*)ws; ws += (size_t)HID * KPAD * 2;
    bf16* w2bt    = (bf16*)ws; ws += (size_t)HID * HID * 2;
    bf16* whbt    = (bf16*)ws; ws += (size_t)NA * HID * 2;
    bf16* h1      = (bf16*)ws; ws += (size_t)BATCH * HID * 2;
    bf16* h2      = (bf16*)ws; ws += (size_t)BATCH * HID * 2;
    bf16* logitsb = (bf16*)ws; ws += (size_t)BATCH * NA * 2;
    unsigned* pact = (unsigned*)ws; ws += (size_t)NA * 4;
    unsigned* trow = (unsigned*)ws; ws += (size_t)BATCH * 4;

    prep_k<<<5808, 256, 0, stream>>>(states, W1, W2, Wh, act,
                                     statesb, w1bt, w2bt, whbt, pact, trow);

    // G1/G2: N=1024 -> BN=64 tiles (1024 blocks; occupancy fix, round 6: -24 us)
    gemm128<0, 64><<<dim3(HID / 64, BATCH / 128), 256, 0, stream>>>(
        statesb, w1bt, b1, h1, BATCH, HID, KPAD, nullptr, nullptr);
    gemm128<0, 64><<<dim3(HID / 64, BATCH / 128), 256, 0, stream>>>(
        h1, w2bt, b2, h2, BATCH, HID, HID, nullptr, nullptr);
    // logits GEMM with fused feasibility log-mask in the epilogue
    gemm128<3, 128><<<dim3(NA / 128, BATCH / 128), 256, 0, stream>>>(
        h2, whbt, bh, logitsb, BATCH, NA, HID, trow, pact);

    softmax_k<<<BATCH / 4, 256, 0, stream>>>(logitsb, out);
}